// Round 1
// baseline (320.818 us; speedup 1.0000x reference)
//
#include <hip/hip_runtime.h>
#include <stdint.h>

#define TPE 4096
#define DM 512
#define HID 1408
#define NE 8

#define N4X   4194304   // 32768*512/4
#define N4W12 2883584   // 8*2816*512/4

typedef unsigned short u16;
typedef __attribute__((ext_vector_type(8))) __bf16 bf16x8;
typedef __attribute__((ext_vector_type(4))) float f32x4;

__device__ __forceinline__ u16 f2bf(float f) {
  union { float f; uint32_t u; } v; v.f = f;
  uint32_t u = v.u;
  u += 0x7fffu + ((u >> 16) & 1u);   // round-to-nearest-even
  return (u16)(u >> 16);
}

// ---------------- f32 -> bf16 convert for x and w12 only -------------------
__global__ void cvt_xw12(const float* __restrict__ x, const float* __restrict__ w12,
                         u16* __restrict__ xb, u16* __restrict__ w12b) {
  int i = blockIdx.x * blockDim.x + threadIdx.x;   // float4 index
  const float* src; u16* dst; int off;
  if (i < N4X) { src = x;   dst = xb;   off = i; }
  else         { src = w12; dst = w12b; off = i - N4X; }
  float4 v = reinterpret_cast<const float4*>(src)[off];
  union { u16 s[4]; uint2 u2; } o;
  o.s[0] = f2bf(v.x); o.s[1] = f2bf(v.y); o.s[2] = f2bf(v.z); o.s[3] = f2bf(v.w);
  reinterpret_cast<uint2*>(dst)[off] = o.u2;
}

// ------------- global->LDS async stage, ROWS x 64 bf16 tile (4 waves) ------
// Row = 128 B. XOR swizzle at 16B-chunk granularity: global chunk c of row r
// lands at LDS chunk c^(r&7) -> b128 reads are 2-way aliased (free, m136).
template <int ROWS>
__device__ __forceinline__ void stage_tile64(u16* lds, const u16* g, int lda,
                                             int wave, int lane) {
  const int srow = lane >> 3;                 // 0..7 within 8-row window
  const int gchunk = (lane & 7) ^ srow;       // schunk ^ (grow & 7)
#pragma unroll
  for (int r = 0; r < ROWS / 32; ++r) {
    const int row0 = (wave * (ROWS / 32) + r) * 8;
    const u16* gp = g + (size_t)(row0 + srow) * lda + gchunk * 8;
    u16* lp = lds + row0 * 64;                // 64 u16 (=128B) per row
    __builtin_amdgcn_global_load_lds((const __attribute__((address_space(1))) void*)gp,
                                     (__attribute__((address_space(3))) void*)lp,
                                     16, 0, 0);
  }
}

// ------------- 8-wave stagers for the 256-row tiles of gemm1 ---------------
__device__ __forceinline__ void stage256(u16* lds, const u16* g, int lda,
                                         int wave, int lane) {
  const int srow = lane >> 3;
  const int gchunk = (lane & 7) ^ srow;
#pragma unroll
  for (int r = 0; r < 4; ++r) {               // 8 waves x 8 rows = 64 rows/issue
    const int row0 = (r * 8 + wave) * 8;
    const u16* gp = g + (size_t)(row0 + srow) * lda + gchunk * 8;
    u16* lp = lds + row0 * 64;
    __builtin_amdgcn_global_load_lds((const __attribute__((address_space(1))) void*)gp,
                                     (__attribute__((address_space(3))) void*)lp,
                                     16, 0, 0);
  }
}

// B tile for gemm1: rows 0..127 = gate rows, rows 128..255 = up rows.
__device__ __forceinline__ void stageB256(u16* lds, const u16* Bg, const u16* Bu,
                                          int wave, int lane) {
  const int srow = lane >> 3;
  const int gchunk = (lane & 7) ^ srow;
#pragma unroll
  for (int r = 0; r < 4; ++r) {
    const int rowblk = r * 8 + wave;          // 0..31 (16 gate + 16 up blocks)
    const int row0 = rowblk * 8;
    const u16* base = (rowblk < 16) ? (Bg + (size_t)row0 * DM)
                                    : (Bu + (size_t)(row0 - 128) * DM);
    const u16* gp = base + (size_t)srow * DM + gchunk * 8;
    u16* lp = lds + row0 * 64;
    __builtin_amdgcn_global_load_lds((const __attribute__((address_space(1))) void*)gp,
                                     (__attribute__((address_space(3))) void*)lp,
                                     16, 0, 0);
  }
}

__device__ __forceinline__ bf16x8 read_frag(const u16* lds, int row, int kchunk) {
  return *reinterpret_cast<const bf16x8*>(&lds[row * 64 + (((kchunk ^ (row & 7)) << 3))]);
}

// ---------------- GEMM1 + fused SwiGLU, 8-wave 4-phase pipeline ------------
// Tile: 256 tokens x (128 gate + 128 up cols), BK=64, double-buffered LDS
// (128 KiB -> 1 block/CU, 8 waves). Per K-tile, 4 phases of 16 MFMA each with
// raw s_barrier pairs (no vmcnt drain); prefetch of tile t+1 is issued in
// phases 0/1 and only drained at the iteration-boundary __syncthreads, so the
// global-load latency hides under ~3 phases of MFMA (T3+T4), with T5 setprio
// around each MFMA cluster.
// grid (8, 176+44): blockIdx.x = e -> flat%8 XCD pin keeps w12_e L2-resident.
// y = mt*11 + nt (nt fastest -> A-tile reused 11x while L2-hot).
// y in [176,220): tail blocks convert w3 f32->bf16 (hidden under GEMM).
__global__ __launch_bounds__(512, 2)
void gemm1_swiglu(const u16* __restrict__ xb, const u16* __restrict__ w12b,
                  u16* __restrict__ hb, const float* __restrict__ w3f,
                  u16* __restrict__ w3b) {
  __shared__ u16 sA[2][256 * 64];
  __shared__ u16 sB[2][256 * 64];
  const int e = blockIdx.x;
  const int y = blockIdx.y;
  const int tid = threadIdx.x;

  if (y >= 176) {   // w3 conversion tail: 352 c-blocks x 4096 float4
    const int c = e + 8 * (y - 176);          // 0..351
    const float4* src = reinterpret_cast<const float4*>(w3f) + (size_t)c * 4096;
    uint2* dst = reinterpret_cast<uint2*>(w3b) + (size_t)c * 4096;
#pragma unroll
    for (int it = 0; it < 8; ++it) {
      float4 v = src[it * 512 + tid];
      union { u16 s[4]; uint2 u2; } o;
      o.s[0] = f2bf(v.x); o.s[1] = f2bf(v.y); o.s[2] = f2bf(v.z); o.s[3] = f2bf(v.w);
      dst[it * 512 + tid] = o.u2;
    }
    return;
  }

  const int mt = y / 11, nt = y % 11;
  const int wave = tid >> 6, lane = tid & 63;
  const int wm = wave >> 2, wn = wave & 3;    // 2 (M) x 4 (N) wave grid
  const int quad = lane >> 4, rr = lane & 15;

  const u16* A  = xb + (size_t)(e * TPE + mt * 256) * DM;
  const u16* Bg = w12b + (size_t)e * (2 * HID) * DM + (size_t)(nt * 128) * DM;
  const u16* Bu = Bg + (size_t)HID * DM;

  f32x4 zero = {0.f, 0.f, 0.f, 0.f};
  f32x4 accg[8][2], accu[8][2];
#pragma unroll
  for (int i = 0; i < 8; ++i)
#pragma unroll
    for (int j = 0; j < 2; ++j) { accg[i][j] = zero; accu[i][j] = zero; }

  // prologue: tile 0 into buffer 0
  stage256(sA[0], A, DM, wave, lane);
  stageB256(sB[0], Bg, Bu, wave, lane);
  __syncthreads();

#pragma unroll 2
  for (int t = 0; t < 8; ++t) {               // 8 K-tiles of 64
    const int cur = t & 1, nxt = cur ^ 1;
    const u16* cA = sA[cur];
    const u16* cB = sB[cur];
    bf16x8 af[4][2], bg[2][2], bu[2][2];

    // ---- phase 0: prefetch A(t+1); read A-half0 + B-gate; MFMA accg[0..3]
    if (t < 7) stage256(sA[nxt], A + (t + 1) * 64, DM, wave, lane);
#pragma unroll
    for (int mi = 0; mi < 4; ++mi)
#pragma unroll
      for (int kk = 0; kk < 2; ++kk)
        af[mi][kk] = read_frag(cA, wm * 128 + mi * 16 + rr, kk * 4 + quad);
#pragma unroll
    for (int ni = 0; ni < 2; ++ni)
#pragma unroll
      for (int kk = 0; kk < 2; ++kk)
        bg[ni][kk] = read_frag(cB, wn * 32 + ni * 16 + rr, kk * 4 + quad);
    __builtin_amdgcn_s_barrier();
    __builtin_amdgcn_s_setprio(1);
#pragma unroll
    for (int mi = 0; mi < 4; ++mi)
#pragma unroll
      for (int ni = 0; ni < 2; ++ni)
#pragma unroll
        for (int kk = 0; kk < 2; ++kk)
          accg[mi][ni] = __builtin_amdgcn_mfma_f32_16x16x32_bf16(af[mi][kk], bg[ni][kk], accg[mi][ni], 0, 0, 0);
    __builtin_amdgcn_s_setprio(0);
    __builtin_amdgcn_s_barrier();

    // ---- phase 1: prefetch B(t+1); read B-up; MFMA accu[0..3]
    if (t < 7) stageB256(sB[nxt], Bg + (t + 1) * 64, Bu + (t + 1) * 64, wave, lane);
#pragma unroll
    for (int ni = 0; ni < 2; ++ni)
#pragma unroll
      for (int kk = 0; kk < 2; ++kk)
        bu[ni][kk] = read_frag(cB, 128 + wn * 32 + ni * 16 + rr, kk * 4 + quad);
    __builtin_amdgcn_s_barrier();
    __builtin_amdgcn_s_setprio(1);
#pragma unroll
    for (int mi = 0; mi < 4; ++mi)
#pragma unroll
      for (int ni = 0; ni < 2; ++ni)
#pragma unroll
        for (int kk = 0; kk < 2; ++kk)
          accu[mi][ni] = __builtin_amdgcn_mfma_f32_16x16x32_bf16(af[mi][kk], bu[ni][kk], accu[mi][ni], 0, 0, 0);
    __builtin_amdgcn_s_setprio(0);
    __builtin_amdgcn_s_barrier();

    // ---- phase 2: read A-half1; MFMA accg[4..7] (B-gate frags held in regs)
#pragma unroll
    for (int mi = 0; mi < 4; ++mi)
#pragma unroll
      for (int kk = 0; kk < 2; ++kk)
        af[mi][kk] = read_frag(cA, wm * 128 + 64 + mi * 16 + rr, kk * 4 + quad);
    __builtin_amdgcn_s_barrier();
    __builtin_amdgcn_s_setprio(1);
#pragma unroll
    for (int mi = 0; mi < 4; ++mi)
#pragma unroll
      for (int ni = 0; ni < 2; ++ni)
#pragma unroll
        for (int kk = 0; kk < 2; ++kk)
          accg[4 + mi][ni] = __builtin_amdgcn_mfma_f32_16x16x32_bf16(af[mi][kk], bg[ni][kk], accg[4 + mi][ni], 0, 0, 0);
    __builtin_amdgcn_s_setprio(0);
    __builtin_amdgcn_s_barrier();

    // ---- phase 3: MFMA accu[4..7]; boundary sync drains prefetch (vmcnt 0)
    __builtin_amdgcn_s_setprio(1);
#pragma unroll
    for (int mi = 0; mi < 4; ++mi)
#pragma unroll
      for (int ni = 0; ni < 2; ++ni)
#pragma unroll
        for (int kk = 0; kk < 2; ++kk)
          accu[4 + mi][ni] = __builtin_amdgcn_mfma_f32_16x16x32_bf16(af[mi][kk], bu[ni][kk], accu[4 + mi][ni], 0, 0, 0);
    __builtin_amdgcn_s_setprio(0);
    __syncthreads();
  }

  // epilogue: SwiGLU combine, write 256x128 h tile (wave owns 128 x 32 cols)
  const size_t rowbase = (size_t)(e * TPE + mt * 256 + wm * 128);
  const int colbase = nt * 128 + wn * 32;
#pragma unroll
  for (int mi = 0; mi < 8; ++mi)
#pragma unroll
    for (int ni = 0; ni < 2; ++ni)
#pragma unroll
      for (int r2 = 0; r2 < 4; ++r2) {
        float g = accg[mi][ni][r2];
        float u = accu[mi][ni][r2];
        float s = (g / (1.f + __expf(-g))) * u;
        size_t row = rowbase + mi * 16 + quad * 4 + r2;
        int col = colbase + ni * 16 + rr;
        hb[row * HID + col] = f2bf(s);
      }
}

// ---------------- GEMM2: h @ w3^T -> out (f32), 128x256, XCD-pinned --------
// grid (8, 64): x = e -> XCD pin (w3_e 1.4 MB L2-resident); y = mt*2 + nt.
__global__ __launch_bounds__(256, 2)
void gemm2(const u16* __restrict__ hb, const u16* __restrict__ w3b,
           float* __restrict__ out) {
  __shared__ u16 sA[128 * 64];
  __shared__ u16 sB[256 * 64];
  const int e = blockIdx.x;
  const int mt = blockIdx.y >> 1, nt = blockIdx.y & 1;
  const int tid = threadIdx.x, wave = tid >> 6, lane = tid & 63;
  const int wm = wave >> 1, wn = wave & 1;
  const int quad = lane >> 4, rr = lane & 15;

  const u16* A = hb + (size_t)(e * TPE + mt * 128) * HID;
  const u16* B = w3b + (size_t)e * DM * HID + (size_t)(nt * 256) * HID;

  f32x4 zero = {0.f, 0.f, 0.f, 0.f};
  f32x4 acc[4][8];
#pragma unroll
  for (int i = 0; i < 4; ++i)
#pragma unroll
    for (int j = 0; j < 8; ++j) acc[i][j] = zero;

  for (int k0 = 0; k0 < HID; k0 += 64) {
    stage_tile64<128>(sA, A + k0, HID, wave, lane);
    stage_tile64<256>(sB, B + k0, HID, wave, lane);
    __syncthreads();

#pragma unroll
    for (int kk = 0; kk < 2; ++kk) {
      const int kc = kk * 4 + quad;
      bf16x8 af[4], bfr[8];
#pragma unroll
      for (int mi = 0; mi < 4; ++mi)
        af[mi] = read_frag(sA, wm * 64 + mi * 16 + rr, kc);
#pragma unroll
      for (int ni = 0; ni < 8; ++ni)
        bfr[ni] = read_frag(sB, wn * 128 + ni * 16 + rr, kc);
#pragma unroll
      for (int mi = 0; mi < 4; ++mi)
#pragma unroll
        for (int ni = 0; ni < 8; ++ni)
          acc[mi][ni] = __builtin_amdgcn_mfma_f32_16x16x32_bf16(af[mi], bfr[ni], acc[mi][ni], 0, 0, 0);
    }
    __syncthreads();
  }

  const size_t rowbase = (size_t)(e * TPE + mt * 128 + wm * 64);
  const int colbase = nt * 256 + wn * 128;
#pragma unroll
  for (int mi = 0; mi < 4; ++mi)
#pragma unroll
    for (int ni = 0; ni < 8; ++ni)
#pragma unroll
      for (int r2 = 0; r2 < 4; ++r2) {
        size_t row = rowbase + mi * 16 + quad * 4 + r2;
        int col = colbase + ni * 16 + rr;
        out[row * DM + col] = acc[mi][ni][r2];
      }
}

// ---------------------------------------------------------------------------
extern "C" void kernel_launch(void* const* d_in, const int* in_sizes, int n_in,
                              void* d_out, int out_size, void* d_ws, size_t ws_size,
                              hipStream_t stream) {
  (void)in_sizes; (void)n_in; (void)out_size; (void)ws_size;
  const float* x   = (const float*)d_in[0];
  const float* w12 = (const float*)d_in[1];
  const float* w3  = (const float*)d_in[2];
  float* out = (float*)d_out;

  char* ws = (char*)d_ws;
  u16* xb   = (u16*)(ws);
  u16* w12b = (u16*)(ws + (size_t)33554432);
  u16* w3b  = (u16*)(ws + (size_t)33554432 + 23068672);
  u16* hb   = (u16*)(ws + (size_t)33554432 + 23068672 + 11534336);

  const int n4 = N4X + N4W12;   // 7,077,888 -> 27648 blocks
  cvt_xw12<<<n4 / 256, 256, 0, stream>>>(x, w12, xb, w12b);

  // gemm1: XCD-pinned (x=e); y = mt*11+nt for tiles, y>=176 converts w3
  gemm1_swiglu<<<dim3(8, 176 + 44), 512, 0, stream>>>(xb, w12b, hb, w3, w3b);
  gemm2<<<dim3(8, 64), 256, 0, stream>>>(hb, w3b, out);
}